// Round 1
// 1044.882 us; speedup vs baseline: 1.2239x; 1.2239x over previous
//
#include <hip/hip_runtime.h>
#include <cstdint>
#include <cstddef>

// ---------- types ----------
typedef __bf16 bf16;
typedef __bf16 bf16x8 __attribute__((ext_vector_type(8)));
typedef float  f32x4  __attribute__((ext_vector_type(4)));
typedef float  f32x16 __attribute__((ext_vector_type(16)));
typedef unsigned short u16x4v __attribute__((ext_vector_type(4)));
typedef unsigned int   u32x4v __attribute__((ext_vector_type(4)));

#define MFMA16(a, b, c) __builtin_amdgcn_mfma_f32_16x16x32_bf16((a), (b), (c), 0, 0, 0)
#define MFMA32(a, b, c) __builtin_amdgcn_mfma_f32_32x32x16_bf16((a), (b), (c), 0, 0, 0)

// async global->LDS, 16B per lane. LDS dst is wave-uniform base + lane*16 (HW adds lane part).
__device__ __forceinline__ void glds16(const bf16* g, bf16* l) {
    __builtin_amdgcn_global_load_lds(
        (__attribute__((address_space(1))) void*)(g),
        (__attribute__((address_space(3))) void*)(l), 16, 0, 0);
}

// pack two f32 -> one u32 of 2x bf16 (no builtin on gfx950; guide T12)
__device__ __forceinline__ unsigned cvtpk_bf16(float lo, float hi) {
    unsigned r;
    asm("v_cvt_pk_bf16_f32 %0, %1, %2" : "=v"(r) : "v"(lo), "v"(hi));
    return r;
}

// ---------- conversion kernels ----------
__global__ __launch_bounds__(256) void cvt_bf16_k(const float* __restrict__ in,
                                                  bf16* __restrict__ out, long long n) {
    long long i = ((long long)blockIdx.x * 256 + threadIdx.x) * 8;
    if (i >= n) return;
    const float4* p = (const float4*)(in + i);
    float4 a = p[0], b = p[1];
    bf16x8 o;
    o[0] = (bf16)a.x; o[1] = (bf16)a.y; o[2] = (bf16)a.z; o[3] = (bf16)a.w;
    o[4] = (bf16)b.x; o[5] = (bf16)b.y; o[6] = (bf16)b.z; o[7] = (bf16)b.w;
    *(bf16x8*)(out + i) = o;
}

// past_k [4][8][1024][128] f32 -> Kcache [4][8][2048][128] bf16 (first 1024 rows)
__global__ __launch_bounds__(256) void cvt_pastk_k(const float* __restrict__ in,
                                                   bf16* __restrict__ Kc) {
    long long e = ((long long)blockIdx.x * 256 + threadIdx.x) * 8;
    long long bh = e >> 17;          // / (1024*128)
    long long rem = e & 131071;
    const float4* p = (const float4*)(in + e);
    float4 a = p[0], b = p[1];
    bf16x8 o;
    o[0] = (bf16)a.x; o[1] = (bf16)a.y; o[2] = (bf16)a.z; o[3] = (bf16)a.w;
    o[4] = (bf16)b.x; o[5] = (bf16)b.y; o[6] = (bf16)b.z; o[7] = (bf16)b.w;
    *(bf16x8*)(Kc + bh * 262144 + rem) = o;
}

// past_v [4][8][1024][128] f32 -> Vt [4][8][128][2048] bf16 (transposed, first 1024 cols)
__global__ __launch_bounds__(256) void cvt_pastv_k(const float* __restrict__ in,
                                                   bf16* __restrict__ Vt) {
    const int tid = blockIdx.x * 256 + threadIdx.x;
    const int d   = tid & 127;
    const int kv4 = (tid >> 7) & 255;
    const int bh  = tid >> 15;
    u16x4v pk;
#pragma unroll
    for (int r = 0; r < 4; ++r) {
        float v = in[((long long)bh * 1024 + kv4 * 4 + r) * 128 + d];
        pk[r] = __builtin_bit_cast(unsigned short, (bf16)v);
    }
    *(u16x4v*)(Vt + ((long long)bh * 128 + d) * 2048 + kv4 * 4) = pk;
}

// attention_mask [4][2048] i32 -> packed u64 [4][32]; bit=1 means MASKED (nonzero)
__global__ void pack_mask_k(const int* __restrict__ am, unsigned long long* __restrict__ mp) {
    const int t = threadIdx.x;          // 128 threads
    if (t >= 128) return;
    const int b = t >> 5, w = t & 31;
    const int* p = am + b * 2048 + w * 64;
    unsigned long long m = 0;
#pragma unroll 8
    for (int i = 0; i < 64; ++i)
        if (p[i] != 0) m |= (1ull << i);
    mp[b * 32 + w] = m;
}

// ---------- GEMM: C[m][n] = sum_k A[m][k]*B[n][k] (+bias), m97-style 128x128 tile ----------
// MODE 0: bf16 row-major out, (acc+bias)*scale
// MODE 1: f32 row-major out, acc+bias            (final output projection)
// MODE 2: bf16 out scattered into K-cache [b][h][2048][128] at rows 1024+s
// MODE 3: bf16 out scattered transposed into Vt [b][h][128][2048] at cols 1024+s
// MODE 4: bf16 out scattered into Qs [b][h][1024][128], (acc+bias)*scale  (Q projection)
template <int MODE>
__global__ __launch_bounds__(256) void gemm_bt(const bf16* __restrict__ A,
                                               const bf16* __restrict__ B,
                                               const float* __restrict__ bias,
                                               void* __restrict__ Cv,
                                               int M, int N, int K, float scale) {
    __shared__ bf16 Asm[128 * 32];
    __shared__ bf16 Bsm[128 * 32];
    const int t = threadIdx.x;
    const int lane = t & 63, w = t >> 6;
    const int quad = lane >> 4, l16 = lane & 15;
    const int wr = (w >> 1) * 64, wc = (w & 1) * 64;
    const long long m0 = (long long)blockIdx.y * 128, n0 = (long long)blockIdx.x * 128;

    f32x4 acc[4][4] = {};

    const int i1 = t, i2 = t + 256;
    const bf16* gA1 = A + (m0 + (i1 >> 2)) * K + (i1 & 3) * 8;
    const bf16* gA2 = A + (m0 + (i2 >> 2)) * K + (i2 & 3) * 8;
    const bf16* gB1 = B + (n0 + (i1 >> 2)) * K + (i1 & 3) * 8;
    const bf16* gB2 = B + (n0 + (i2 >> 2)) * K + (i2 & 3) * 8;
    bf16* lA1 = Asm + i1 * 8;
    bf16* lA2 = Asm + i2 * 8;
    bf16* lB1 = Bsm + i1 * 8;
    bf16* lB2 = Bsm + i2 * 8;

    for (int k0 = 0; k0 < K; k0 += 32) {
        glds16(gA1 + k0, lA1);
        glds16(gA2 + k0, lA2);
        glds16(gB1 + k0, lB1);
        glds16(gB2 + k0, lB2);
        __syncthreads();
        bf16x8 af[4], bfr[4];
#pragma unroll
        for (int i = 0; i < 4; ++i)
            af[i] = *(const bf16x8*)(Asm + (wr + i * 16 + l16) * 32 + quad * 8);
#pragma unroll
        for (int j = 0; j < 4; ++j)
            bfr[j] = *(const bf16x8*)(Bsm + (wc + j * 16 + l16) * 32 + quad * 8);
#pragma unroll
        for (int i = 0; i < 4; ++i)
#pragma unroll
            for (int j = 0; j < 4; ++j)
                acc[i][j] = MFMA16(af[i], bfr[j], acc[i][j]);
        __syncthreads();
    }

    float bs[4];
#pragma unroll
    for (int j = 0; j < 4; ++j) bs[j] = bias[n0 + wc + j * 16 + l16];

#pragma unroll
    for (int i = 0; i < 4; ++i) {
        const long long mbase = m0 + wr + i * 16 + quad * 4;
#pragma unroll
        for (int j = 0; j < 4; ++j) {
            const long long n = n0 + wc + j * 16 + l16;
            if (MODE == 0) {
                bf16* Cb = (bf16*)Cv;
#pragma unroll
                for (int r = 0; r < 4; ++r)
                    Cb[(mbase + r) * N + n] = (bf16)((acc[i][j][r] + bs[j]) * scale);
            } else if (MODE == 1) {
                float* Cf = (float*)Cv;
#pragma unroll
                for (int r = 0; r < 4; ++r)
                    Cf[(mbase + r) * N + n] = acc[i][j][r] + bs[j];
            } else if (MODE == 2) {
                bf16* Ck = (bf16*)Cv;
                const int h = (int)(n >> 7), d = (int)(n & 127);
#pragma unroll
                for (int r = 0; r < 4; ++r) {
                    const long long m = mbase + r;
                    const long long bb = m >> 10, s = m & 1023;
                    Ck[((bb * 8 + h) * 2048 + 1024 + s) * 128 + d] = (bf16)(acc[i][j][r] + bs[j]);
                }
            } else if (MODE == 3) {
                bf16* Cvt = (bf16*)Cv;
                const int h = (int)(n >> 7), d = (int)(n & 127);
                const long long bb = mbase >> 10, s = mbase & 1023;
                u16x4v pk;
#pragma unroll
                for (int r = 0; r < 4; ++r)
                    pk[r] = __builtin_bit_cast(unsigned short, (bf16)(acc[i][j][r] + bs[j]));
                *(u16x4v*)(Cvt + ((bb * 8 + h) * 128 + d) * 2048 + 1024 + s) = pk;
            } else {  // MODE 4: Qs [b][h][1024][128] bf16, scaled
                bf16* Cq = (bf16*)Cv;
                const int h = (int)(n >> 7), d = (int)(n & 127);
#pragma unroll
                for (int r = 0; r < 4; ++r) {
                    const long long m = mbase + r;
                    const long long bb = m >> 10, s = m & 1023;
                    Cq[((bb * 32 + h) * 1024 + s) * 128 + d] = (bf16)((acc[i][j][r] + bs[j]) * scale);
                }
            }
        }
    }
}

// ---------- flash attention (8-wave, 32x32 swapped-MFMA, in-register softmax) ----------
// Q pre-scaled by log2e/sqrt(128); softmax in base 2.
// Grid: 512 blocks x 512 threads. Each wave owns 32 q-rows; block = 256 q-rows of one (b,h).
// S^T = mfma(K, Q): lane holds full P-row for q = lane&31 (16 regs/half, partner lane has rest).
// O^T = mfma(Vt, P): col = q = lane&31 -> softmax stats stay per-lane scalars.
__global__ __launch_bounds__(512, 2) void attn_k(const bf16* __restrict__ Qs,
                                                 const bf16* __restrict__ Kc,
                                                 const bf16* __restrict__ Vt,
                                                 const unsigned long long* __restrict__ mpack,
                                                 bf16* __restrict__ AO) {
    // XCD-chunked bijective swizzle (512 % 8 == 0): each XCD gets 64 consecutive logical blocks
    const int phys = blockIdx.x;
    const int lid = (phys & 7) * 64 + (phys >> 3);
    const int qt = lid & 3, h = (lid >> 2) & 31, b = lid >> 7;
    const int hk = h >> 2;
    const int t = threadIdx.x, lane = t & 63, w = t >> 6;
    const int q32 = lane & 31, half = lane >> 5;

    __shared__ bf16 Ksm[2][64 * 128];   // [kv][d], XOR-swizzled 16B slots: slot ^= row&7
    __shared__ bf16 Vsm[2][128 * 64];   // [d][kv], XOR-swizzled 16B slots: slot ^= row&7

    const bf16* kg = Kc + (long long)(b * 8 + hk) * 2048 * 128;
    const bf16* vg = Vt + (long long)(b * 8 + hk) * 128 * 2048;
    const unsigned long long* mrow = mpack + b * 32;

    // Q B-fragments: q-row = lane&31, k = d = kw*16 + half*8 + i
    bf16x8 qf[8];
    {
        const bf16* qb = Qs + ((long long)(b * 32 + h) * 1024 + qt * 256 + w * 32 + q32) * 128 + half * 8;
#pragma unroll
        for (int kw = 0; kw < 8; ++kw) qf[kw] = *(const bf16x8*)(qb + kw * 16);
    }

    f32x16 Ot[4] = {};                  // O^T accum: C-layout row = d, col = q = lane&31
    float mi = -1e30f, li = 0.f;

    // staging geometry (global src carries the inverse swizzle; LDS dst is linear)
    const int krow = lane >> 4, kslot = lane & 15;   // K: 4 rows x 16 slots (16B) per instr
    const int vrow = lane >> 3, vslot = lane & 7;    // V: 8 rows x 8 slots (16B) per instr

#define STAGE(BUF, KV0) do {                                                                  \
        const int kr0 = w * 8 + krow;                                                         \
        glds16(kg + (long long)((KV0) + kr0) * 128 + ((kslot ^ (kr0 & 7)) * 8),               \
               &Ksm[BUF][(w * 8) * 128]);                                                     \
        const int kr1 = kr0 + 4;                                                              \
        glds16(kg + (long long)((KV0) + kr1) * 128 + ((kslot ^ (kr1 & 7)) * 8),               \
               &Ksm[BUF][(w * 8 + 4) * 128]);                                                 \
        const int vd0 = w * 16 + vrow;                                                        \
        glds16(vg + (long long)vd0 * 2048 + (KV0) + ((vslot ^ (vrow & 7)) * 8),               \
               &Vsm[BUF][(w * 16) * 64]);                                                     \
        const int vd1 = vd0 + 8;                                                              \
        glds16(vg + (long long)vd1 * 2048 + (KV0) + ((vslot ^ (vrow & 7)) * 8),               \
               &Vsm[BUF][(w * 16 + 8) * 64]);                                                 \
    } while (0)

    STAGE(0, 0);
    __syncthreads();

    int buf = 0;
    for (int tt = 0; tt < 32; ++tt) {
        if (tt < 31) STAGE(buf ^ 1, tt * 64 + 64);   // async prefetch; drained by barrier below

        // ---- S^T = K Q^T : C rows = kv, cols = q (lane&31) ----
        f32x16 s0 = {}, s1 = {};
        __builtin_amdgcn_s_setprio(1);
#pragma unroll
        for (int kw = 0; kw < 8; ++kw) {
            const int sl = ((kw * 2 + half) ^ (q32 & 7)) * 8;
            bf16x8 k0 = *(const bf16x8*)(&Ksm[buf][q32 * 128 + sl]);
            bf16x8 k1 = *(const bf16x8*)(&Ksm[buf][(32 + q32) * 128 + sl]);
            s0 = MFMA32(k0, qf[kw], s0);
            s1 = MFMA32(k1, qf[kw], s1);
        }
        __builtin_amdgcn_s_setprio(0);

        // ---- mask (uniform u64 per 64-kv tile; zero on the all-attend bench) ----
        const unsigned long long mw = mrow[tt];
        if (mw) {
#pragma unroll
            for (int g = 0; g < 4; ++g)
#pragma unroll
                for (int j = 0; j < 4; ++j) {
                    const int kl = j + 8 * g + 4 * half;
                    if ((mw >> kl) & 1) s0[g * 4 + j] = -1e30f;
                    if ((mw >> (32 + kl)) & 1) s1[g * 4 + j] = -1e30f;
                }
        }

        // ---- row max: 4 chains in-register + one cross-half permlane swap ----
        float m0 = fmaxf(s0[0], s1[0]), m1 = fmaxf(s0[1], s1[1]);
        float m2 = fmaxf(s0[2], s1[2]), m3 = fmaxf(s0[3], s1[3]);
#pragma unroll
        for (int i = 4; i < 16; i += 4) {
            m0 = fmaxf(m0, fmaxf(s0[i + 0], s1[i + 0]));
            m1 = fmaxf(m1, fmaxf(s0[i + 1], s1[i + 1]));
            m2 = fmaxf(m2, fmaxf(s0[i + 2], s1[i + 2]));
            m3 = fmaxf(m3, fmaxf(s0[i + 3], s1[i + 3]));
        }
        float mx = fmaxf(fmaxf(m0, m1), fmaxf(m2, m3));
        {
            auto r = __builtin_amdgcn_permlane32_swap(__builtin_bit_cast(unsigned, mx),
                                                      __builtin_bit_cast(unsigned, mx), false, false);
            mx = fmaxf(mx, fmaxf(__builtin_bit_cast(float, (unsigned)r[0]),
                                 __builtin_bit_cast(float, (unsigned)r[1])));
        }

        // ---- defer-max (T13): only rescale when max grew by > 8 (log2 domain) ----
        if (__any(mx > mi + 8.f)) {
            const float mnew = fmaxf(mi, mx);
            const float al = exp2f(mi - mnew);
            mi = mnew;
            li *= al;
#pragma unroll
            for (int dt = 0; dt < 4; ++dt)
#pragma unroll
                for (int i = 0; i < 16; ++i) Ot[dt][i] *= al;
        }

        // ---- P = exp2(S - mi), 4 accumulation chains; cross-half sum swap ----
        float a0 = 0.f, a1 = 0.f, a2 = 0.f, a3 = 0.f;
#pragma unroll
        for (int i = 0; i < 16; i += 4) {
            float p;
            p = exp2f(s0[i + 0] - mi); s0[i + 0] = p; a0 += p;
            p = exp2f(s0[i + 1] - mi); s0[i + 1] = p; a1 += p;
            p = exp2f(s0[i + 2] - mi); s0[i + 2] = p; a2 += p;
            p = exp2f(s0[i + 3] - mi); s0[i + 3] = p; a3 += p;
            p = exp2f(s1[i + 0] - mi); s1[i + 0] = p; a0 += p;
            p = exp2f(s1[i + 1] - mi); s1[i + 1] = p; a1 += p;
            p = exp2f(s1[i + 2] - mi); s1[i + 2] = p; a2 += p;
            p = exp2f(s1[i + 3] - mi); s1[i + 3] = p; a3 += p;
        }
        float sum = (a0 + a1) + (a2 + a3);
        {
            auto r = __builtin_amdgcn_permlane32_swap(__builtin_bit_cast(unsigned, sum),
                                                      __builtin_bit_cast(unsigned, sum), false, false);
            sum += __builtin_bit_cast(float, (unsigned)(half ? r[0] : r[1]));
        }
        li += sum;

        // ---- P -> bf16 A/B-fragments, fully in-register (T12: cvt_pk + permlane32_swap) ----
        // pf[kvw] element i = P[q=lane&31][kvw*16 + half*8 + i]
        bf16x8 pf[4];
#pragma unroll
        for (int s32 = 0; s32 < 2; ++s32)
#pragma unroll
            for (int wp = 0; wp < 2; ++wp) {
                const f32x16& st = s32 ? s1 : s0;
                unsigned xa = cvtpk_bf16(st[8 * wp + 0], st[8 * wp + 1]);
                unsigned xb = cvtpk_bf16(st[8 * wp + 2], st[8 * wp + 3]);
                unsigned ya = cvtpk_bf16(st[8 * wp + 4], st[8 * wp + 5]);
                unsigned yb = cvtpk_bf16(st[8 * wp + 6], st[8 * wp + 7]);
                auto rA = __builtin_amdgcn_permlane32_swap(xa, ya, false, false);
                auto rB = __builtin_amdgcn_permlane32_swap(xb, yb, false, false);
                u32x4v fw;
                fw[0] = (unsigned)rA[0]; fw[1] = (unsigned)rB[0];
                fw[2] = (unsigned)rA[1]; fw[3] = (unsigned)rB[1];
                pf[s32 * 2 + wp] = __builtin_bit_cast(bf16x8, fw);
            }

        // ---- O^T += Vt P : A = Vt rows (d), B = P (col q) ----
        __builtin_amdgcn_s_setprio(1);
#pragma unroll
        for (int kvw = 0; kvw < 4; ++kvw) {
            const int sl = ((kvw * 2 + half) ^ (q32 & 7)) * 8;
#pragma unroll
            for (int dt = 0; dt < 4; ++dt) {
                bf16x8 vf = *(const bf16x8*)(&Vsm[buf][(dt * 32 + q32) * 64 + sl]);
                Ot[dt] = MFMA32(vf, pf[kvw], Ot[dt]);
            }
        }
        __builtin_amdgcn_s_setprio(0);

        __syncthreads();   // drains this tile's reads AND the prefetch vmcnt (compiler-inserted)
        buf ^= 1;
    }
#undef STAGE

    // ---- epilogue: normalize, store bf16 [token][h*128+d] ----
    const float inv = 1.f / li;
    const long long token = (long long)b * 1024 + qt * 256 + w * 32 + q32;
    bf16* ao = AO + token * 4096 + h * 128 + half * 4;
#pragma unroll
    for (int dt = 0; dt < 4; ++dt)
#pragma unroll
        for (int g = 0; g < 4; ++g) {
            u16x4v pk;
#pragma unroll
            for (int j = 0; j < 4; ++j)
                pk[j] = __builtin_bit_cast(unsigned short, (bf16)(Ot[dt][g * 4 + j] * inv));
            *(u16x4v*)(ao + dt * 32 + g * 8) = pk;
        }
}

// ---------- host launch ----------
extern "C" void kernel_launch(void* const* d_in, const int* in_sizes, int n_in,
                              void* d_out, int out_size, void* d_ws, size_t ws_size,
                              hipStream_t stream) {
    const float* hidden = (const float*)d_in[0];
    const float* past_k = (const float*)d_in[1];
    const float* past_v = (const float*)d_in[2];
    const int*   amask  = (const int*)d_in[3];
    const float* Wq = (const float*)d_in[4];
    const float* bq = (const float*)d_in[5];
    const float* Wk = (const float*)d_in[6];
    const float* bk = (const float*)d_in[7];
    const float* Wv = (const float*)d_in[8];
    const float* bv = (const float*)d_in[9];
    const float* Wo = (const float*)d_in[10];
    const float* bo = (const float*)d_in[11];

    // workspace layout (128 MB total)
    char* ws = (char*)d_ws;
    bf16* Xb  = (bf16*)(ws);                     // 32 MB  hidden bf16 [4096][4096]
    bf16* Wqb = (bf16*)(ws + (1ll << 25));       // 32 MB: Wq bf16, later reused for Wo
    bf16* Kb  = (bf16*)(ws + (1ll << 26));       // 64MB:  K cache bf16 [4][8][2048][128]
    bf16* Vtb = (bf16*)(ws + (1ll << 26) + (1ll << 24)); // 80MB: V^T cache [4][8][128][2048]
    bf16* AOb = (bf16*)(ws + (3ll << 25));       // 96MB:  attention out bf16 [4096][4096]
    // scratch inside d_out (64MB, dead before final GEMM writes it)
    char* oc = (char*)d_out;
    bf16* Qb  = (bf16*)(oc);                     // 32 MB: scaled Q bf16 [4][32][1024][128]
    bf16* Wkb = (bf16*)(oc + (1ll << 25));       // 8 MB
    bf16* Wvb = (bf16*)(oc + (1ll << 25) + (1ll << 23)); // 8 MB
    unsigned long long* mpk = (unsigned long long*)(oc + (3ll << 24)); // 48MB: packed mask, 1KB

    const float qscale = 0.08838834764831845f * 1.44269504088896340f; // 1/sqrt(128) * log2(e)

    cvt_bf16_k<<<8192, 256, 0, stream>>>(hidden, Xb, 16777216ll);
    cvt_bf16_k<<<8192, 256, 0, stream>>>(Wq, Wqb, 16777216ll);
    cvt_bf16_k<<<2048, 256, 0, stream>>>(Wk, Wkb, 4194304ll);
    cvt_bf16_k<<<2048, 256, 0, stream>>>(Wv, Wvb, 4194304ll);
    cvt_pastk_k<<<2048, 256, 0, stream>>>(past_k, Kb);
    cvt_pastv_k<<<4096, 256, 0, stream>>>(past_v, Vtb);
    pack_mask_k<<<1, 128, 0, stream>>>(amask, mpk);

    gemm_bt<4><<<dim3(32, 32), 256, 0, stream>>>(Xb, Wqb, bq, (void*)Qb, 4096, 4096, 4096, qscale);
    gemm_bt<2><<<dim3(8, 32), 256, 0, stream>>>(Xb, Wkb, bk, (void*)Kb, 4096, 1024, 4096, 1.0f);
    gemm_bt<3><<<dim3(8, 32), 256, 0, stream>>>(Xb, Wvb, bv, (void*)Vtb, 4096, 1024, 4096, 1.0f);

    // Wo -> bf16 (reuse Wqb buffer; stream-ordered after Q projection consumed it)
    cvt_bf16_k<<<8192, 256, 0, stream>>>(Wo, Wqb, 16777216ll);

    attn_k<<<512, 512, 0, stream>>>(Qb, Kb, Vtb, mpk, AOb);

    gemm_bt<1><<<dim3(32, 32), 256, 0, stream>>>(AOb, Wqb, bo, d_out, 4096, 4096, 4096, 1.0f);
}

// Round 2
// 889.702 us; speedup vs baseline: 1.4374x; 1.1744x over previous
//
#include <hip/hip_runtime.h>
#include <cstdint>
#include <cstddef>

// ---------- types ----------
typedef __bf16 bf16;
typedef __bf16 bf16x8 __attribute__((ext_vector_type(8)));
typedef float  f32x4  __attribute__((ext_vector_type(4)));
typedef float  f32x16 __attribute__((ext_vector_type(16)));
typedef unsigned short u16x4v __attribute__((ext_vector_type(4)));
typedef unsigned int   u32x4v __attribute__((ext_vector_type(4)));

#define MFMA16(a, b, c) __builtin_amdgcn_mfma_f32_16x16x32_bf16((a), (b), (c), 0, 0, 0)
#define MFMA32(a, b, c) __builtin_amdgcn_mfma_f32_32x32x16_bf16((a), (b), (c), 0, 0, 0)

// async global->LDS, 16B per lane. LDS dst is wave-uniform base + lane*16 (HW adds lane part).
__device__ __forceinline__ void glds16(const bf16* g, bf16* l) {
    __builtin_amdgcn_global_load_lds(
        (__attribute__((address_space(1))) void*)(g),
        (__attribute__((address_space(3))) void*)(l), 16, 0, 0);
}

// pack two f32 -> one u32 of 2x bf16 (no builtin on gfx950; guide T12)
__device__ __forceinline__ unsigned cvtpk_bf16(float lo, float hi) {
    unsigned r;
    asm("v_cvt_pk_bf16_f32 %0, %1, %2" : "=v"(r) : "v"(lo), "v"(hi));
    return r;
}

// ---------- conversion kernels ----------
__global__ __launch_bounds__(256) void cvt_bf16_k(const float* __restrict__ in,
                                                  bf16* __restrict__ out, long long n) {
    long long i = ((long long)blockIdx.x * 256 + threadIdx.x) * 8;
    if (i >= n) return;
    const float4* p = (const float4*)(in + i);
    float4 a = p[0], b = p[1];
    bf16x8 o;
    o[0] = (bf16)a.x; o[1] = (bf16)a.y; o[2] = (bf16)a.z; o[3] = (bf16)a.w;
    o[4] = (bf16)b.x; o[5] = (bf16)b.y; o[6] = (bf16)b.z; o[7] = (bf16)b.w;
    *(bf16x8*)(out + i) = o;
}

// past_k [4][8][1024][128] f32 -> Kcache [4][8][2048][128] bf16 (first 1024 rows)
__global__ __launch_bounds__(256) void cvt_pastk_k(const float* __restrict__ in,
                                                   bf16* __restrict__ Kc) {
    long long e = ((long long)blockIdx.x * 256 + threadIdx.x) * 8;
    long long bh = e >> 17;          // / (1024*128)
    long long rem = e & 131071;
    const float4* p = (const float4*)(in + e);
    float4 a = p[0], b = p[1];
    bf16x8 o;
    o[0] = (bf16)a.x; o[1] = (bf16)a.y; o[2] = (bf16)a.z; o[3] = (bf16)a.w;
    o[4] = (bf16)b.x; o[5] = (bf16)b.y; o[6] = (bf16)b.z; o[7] = (bf16)b.w;
    *(bf16x8*)(Kc + bh * 262144 + rem) = o;
}

// past_v [4][8][1024][128] f32 -> Vt [4][8][128][2048] bf16 (transposed, first 1024 cols)
__global__ __launch_bounds__(256) void cvt_pastv_k(const float* __restrict__ in,
                                                   bf16* __restrict__ Vt) {
    const int tid = blockIdx.x * 256 + threadIdx.x;
    const int d   = tid & 127;
    const int kv4 = (tid >> 7) & 255;
    const int bh  = tid >> 15;
    u16x4v pk;
#pragma unroll
    for (int r = 0; r < 4; ++r) {
        float v = in[((long long)bh * 1024 + kv4 * 4 + r) * 128 + d];
        pk[r] = __builtin_bit_cast(unsigned short, (bf16)v);
    }
    *(u16x4v*)(Vt + ((long long)bh * 128 + d) * 2048 + kv4 * 4) = pk;
}

// attention_mask [4][2048] i32 -> packed u64 [4][32]; bit=1 means MASKED (nonzero)
__global__ void pack_mask_k(const int* __restrict__ am, unsigned long long* __restrict__ mp) {
    const int t = threadIdx.x;          // 128 threads
    if (t >= 128) return;
    const int b = t >> 5, w = t & 31;
    const int* p = am + b * 2048 + w * 64;
    unsigned long long m = 0;
#pragma unroll 8
    for (int i = 0; i < 64; ++i)
        if (p[i] != 0) m |= (1ull << i);
    mp[b * 32 + w] = m;
}

// ---------- 128x128-tile GEMM (kept for K/V projections, N=1024) ----------
// MODE 2: bf16 out scattered into K-cache [b][h][2048][128] at rows 1024+s
// MODE 3: bf16 out scattered transposed into Vt [b][h][128][2048] at cols 1024+s
template <int MODE>
__global__ __launch_bounds__(256) void gemm_bt(const bf16* __restrict__ A,
                                               const bf16* __restrict__ B,
                                               const float* __restrict__ bias,
                                               void* __restrict__ Cv,
                                               int M, int N, int K, float scale) {
    __shared__ bf16 Asm[128 * 32];
    __shared__ bf16 Bsm[128 * 32];
    const int t = threadIdx.x;
    const int lane = t & 63, w = t >> 6;
    const int quad = lane >> 4, l16 = lane & 15;
    const int wr = (w >> 1) * 64, wc = (w & 1) * 64;
    const long long m0 = (long long)blockIdx.y * 128, n0 = (long long)blockIdx.x * 128;

    f32x4 acc[4][4] = {};

    const int i1 = t, i2 = t + 256;
    const bf16* gA1 = A + (m0 + (i1 >> 2)) * K + (i1 & 3) * 8;
    const bf16* gA2 = A + (m0 + (i2 >> 2)) * K + (i2 & 3) * 8;
    const bf16* gB1 = B + (n0 + (i1 >> 2)) * K + (i1 & 3) * 8;
    const bf16* gB2 = B + (n0 + (i2 >> 2)) * K + (i2 & 3) * 8;
    bf16* lA1 = Asm + i1 * 8;
    bf16* lA2 = Asm + i2 * 8;
    bf16* lB1 = Bsm + i1 * 8;
    bf16* lB2 = Bsm + i2 * 8;

    for (int k0 = 0; k0 < K; k0 += 32) {
        glds16(gA1 + k0, lA1);
        glds16(gA2 + k0, lA2);
        glds16(gB1 + k0, lB1);
        glds16(gB2 + k0, lB2);
        __syncthreads();
        bf16x8 af[4], bfr[4];
#pragma unroll
        for (int i = 0; i < 4; ++i)
            af[i] = *(const bf16x8*)(Asm + (wr + i * 16 + l16) * 32 + quad * 8);
#pragma unroll
        for (int j = 0; j < 4; ++j)
            bfr[j] = *(const bf16x8*)(Bsm + (wc + j * 16 + l16) * 32 + quad * 8);
#pragma unroll
        for (int i = 0; i < 4; ++i)
#pragma unroll
            for (int j = 0; j < 4; ++j)
                acc[i][j] = MFMA16(af[i], bfr[j], acc[i][j]);
        __syncthreads();
    }

    float bs[4];
#pragma unroll
    for (int j = 0; j < 4; ++j) bs[j] = bias[n0 + wc + j * 16 + l16];

#pragma unroll
    for (int i = 0; i < 4; ++i) {
        const long long mbase = m0 + wr + i * 16 + quad * 4;
#pragma unroll
        for (int j = 0; j < 4; ++j) {
            const long long n = n0 + wc + j * 16 + l16;
            if (MODE == 2) {
                bf16* Ck = (bf16*)Cv;
                const int h = (int)(n >> 7), d = (int)(n & 127);
#pragma unroll
                for (int r = 0; r < 4; ++r) {
                    const long long m = mbase + r;
                    const long long bb = m >> 10, s = m & 1023;
                    Ck[((bb * 8 + h) * 2048 + 1024 + s) * 128 + d] = (bf16)(acc[i][j][r] + bs[j]);
                }
            } else {  // MODE 3
                bf16* Cvt = (bf16*)Cv;
                const int h = (int)(n >> 7), d = (int)(n & 127);
                const long long bb = mbase >> 10, s = mbase & 1023;
                u16x4v pk;
#pragma unroll
                for (int r = 0; r < 4; ++r)
                    pk[r] = __builtin_bit_cast(unsigned short, (bf16)(acc[i][j][r] + bs[j]));
                *(u16x4v*)(Cvt + ((bb * 8 + h) * 128 + d) * 2048 + 1024 + s) = pk;
            }
        }
    }
}

// ---------- 256x256-tile deep-pipelined GEMM (big projections) ----------
// 8 waves (2M x 4N), BK=32, 4-deep LDS ring, counted vmcnt(8), T2 swizzle, T5 setprio.
// LDS tile layout: 128B lines hold 2 logical rows; 16B slot XOR-swizzled by line&7.
//   logical (row,kk) -> line L=row>>1, slot=(((row&1)*4+(kk>>3)) ^ (L&7)), byte=kk%8*2... (16B granules)
// glds dest is linear; the global SOURCE carries the same (involutive) permutation.
// MODE 1: f32 row-major out, acc+bias           (output projection)
// MODE 4: bf16 out scattered into Qs [b][h][1024][128], (acc+bias)*scale  (Q projection)
template <int MODE>
__global__ __launch_bounds__(512, 2) void gemm256(const bf16* __restrict__ A,
                                                  const bf16* __restrict__ B,
                                                  const float* __restrict__ bias,
                                                  void* __restrict__ Cv,
                                                  int M, int N, int K, float scale) {
    __shared__ bf16 S[4][16384];   // 4 buffers x (A 8192 + B 8192) elems = 128 KiB
    const int t = threadIdx.x, lane = t & 63, w = t >> 6;
    const int quad = lane >> 4, l16 = lane & 15;
    const int wm = w >> 2, wn = w & 3;

    // XCD-chunked bijective swizzle (nwg % 8 == 0 for all our launches)
    const int nwg = gridDim.x * gridDim.y;
    const int bid = blockIdx.y * gridDim.x + blockIdx.x;
    const int lid = (bid & 7) * (nwg >> 3) + (bid >> 3);
    const long long m0 = (long long)(lid / gridDim.x) * 256;
    const long long n0 = (long long)(lid % gridDim.x) * 256;

    // ---- staging geometry: chunk c = 16 rows (8 lines); lane l writes phys slot l&7 of line 8c+(l>>3)
    //      logical slot s = (l&7)^(l>>3); row = 16c + 2*(l>>3) + (s>>2); kk = (s&3)*8
    const int sA   = (lane & 7) ^ (lane >> 3);
    const int rsub = 2 * (lane >> 3) + (sA >> 2);
    const int colk = (sA & 3) * 8;
    const int c0 = w * 2, c1 = w * 2 + 1;
    const long long gA0 = (m0 + c0 * 16 + rsub) * (long long)K + colk;
    const long long gA1 = (m0 + c1 * 16 + rsub) * (long long)K + colk;
    const long long gB0 = (n0 + c0 * 16 + rsub) * (long long)K + colk;
    const long long gB1 = (n0 + c1 * 16 + rsub) * (long long)K + colk;

    // ---- read geometry: frag (m): row = wm*128+m*16+l16, kk = quad*8
    //      line&7 = l16>>1 (indep of m); elem base below, m stride = 512 elems (8 lines)
    const int lA7   = l16 >> 1;
    const int slotE = ((((l16 & 1) * 4 + quad) ^ lA7) * 16) >> 1;   // bytes->elems
    const int baseAe = (wm * 64 + lA7) * 64 + slotE;
    const int baseBe = (wn * 32 + lA7) * 64 + slotE;

    f32x4 acc[8][4] = {};

    auto stg = [&](int bufi, int tile) {
        const long long kk = (long long)tile * 32;
        bf16* sb = &S[bufi][0];
        glds16(A + gA0 + kk, sb + c0 * 512);
        glds16(A + gA1 + kk, sb + c1 * 512);
        glds16(B + gB0 + kk, sb + 8192 + c0 * 512);
        glds16(B + gB1 + kk, sb + 8192 + c1 * 512);
    };
    auto compute = [&](int tt) {
        const bf16* pA = &S[tt & 3][baseAe];
        const bf16* pB = &S[tt & 3][8192 + baseBe];
        bf16x8 af[8], bfr[4];
#pragma unroll
        for (int m = 0; m < 8; ++m) af[m] = *(const bf16x8*)(pA + m * 512);
#pragma unroll
        for (int n = 0; n < 4; ++n) bfr[n] = *(const bf16x8*)(pB + n * 512);
        __builtin_amdgcn_s_setprio(1);
#pragma unroll
        for (int m = 0; m < 8; ++m)
#pragma unroll
            for (int n = 0; n < 4; ++n)
                acc[m][n] = MFMA16(af[m], bfr[n], acc[m][n]);
        __builtin_amdgcn_s_setprio(0);
    };

    const int nt = K >> 5;   // 128 for K=4096

    // prologue: stage tiles 0..2; wait tile 0 (12 issued, <=8 outstanding => tile0 landed)
    stg(0, 0); stg(1, 1); stg(2, 2);
    asm volatile("s_waitcnt vmcnt(8)" ::: "memory");
    asm volatile("s_barrier" ::: "memory");

    // main loop: stage t+3, compute t, counted vmcnt(8) => tile t+1 landed block-wide.
    // Buffer (t+3)&3 == (t-1)&3 was fully lgkm-drained before the previous barrier -> safe.
    for (int tt = 0; tt + 3 < nt; ++tt) {
        stg((tt + 3) & 3, tt + 3);
        compute(tt);
        asm volatile("s_waitcnt vmcnt(8)" ::: "memory");
        asm volatile("s_barrier" ::: "memory");
    }
    // tail peel: outstanding shrinks, so counted waits step down 8 -> 4 -> 0
    compute(nt - 3);
    asm volatile("s_waitcnt vmcnt(4)" ::: "memory");
    asm volatile("s_barrier" ::: "memory");
    compute(nt - 2);
    asm volatile("s_waitcnt vmcnt(0)" ::: "memory");
    asm volatile("s_barrier" ::: "memory");
    compute(nt - 1);

    // ---- epilogue ----
    float bs[4];
#pragma unroll
    for (int n = 0; n < 4; ++n) bs[n] = bias[n0 + wn * 64 + n * 16 + l16];

#pragma unroll
    for (int m = 0; m < 8; ++m) {
        const long long mbase = m0 + wm * 128 + m * 16 + quad * 4;
#pragma unroll
        for (int n = 0; n < 4; ++n) {
            const long long nn = n0 + wn * 64 + n * 16 + l16;
            if (MODE == 1) {
                float* Cf = (float*)Cv;
#pragma unroll
                for (int r = 0; r < 4; ++r)
                    Cf[(mbase + r) * N + nn] = acc[m][n][r] + bs[n];
            } else {  // MODE 4: Qs [b][h][1024][128] bf16, scaled
                bf16* Cq = (bf16*)Cv;
                const int h = (int)(nn >> 7), d = (int)(nn & 127);
#pragma unroll
                for (int r = 0; r < 4; ++r) {
                    const long long mr = mbase + r;
                    const long long bb = mr >> 10, s = mr & 1023;
                    Cq[((bb * 32 + h) * 1024 + s) * 128 + d] = (bf16)((acc[m][n][r] + bs[n]) * scale);
                }
            }
        }
    }
}

// ---------- flash attention (8-wave, 32x32 swapped-MFMA, in-register softmax) ----------
__global__ __launch_bounds__(512, 2) void attn_k(const bf16* __restrict__ Qs,
                                                 const bf16* __restrict__ Kc,
                                                 const bf16* __restrict__ Vt,
                                                 const unsigned long long* __restrict__ mpack,
                                                 bf16* __restrict__ AO) {
    const int phys = blockIdx.x;
    const int lid = (phys & 7) * 64 + (phys >> 3);
    const int qt = lid & 3, h = (lid >> 2) & 31, b = lid >> 7;
    const int hk = h >> 2;
    const int t = threadIdx.x, lane = t & 63, w = t >> 6;
    const int q32 = lane & 31, half = lane >> 5;

    __shared__ bf16 Ksm[2][64 * 128];   // [kv][d], XOR-swizzled 16B slots: slot ^= row&7
    __shared__ bf16 Vsm[2][128 * 64];   // [d][kv], XOR-swizzled 16B slots: slot ^= row&7

    const bf16* kg = Kc + (long long)(b * 8 + hk) * 2048 * 128;
    const bf16* vg = Vt + (long long)(b * 8 + hk) * 128 * 2048;
    const unsigned long long* mrow = mpack + b * 32;

    bf16x8 qf[8];
    {
        const bf16* qb = Qs + ((long long)(b * 32 + h) * 1024 + qt * 256 + w * 32 + q32) * 128 + half * 8;
#pragma unroll
        for (int kw = 0; kw < 8; ++kw) qf[kw] = *(const bf16x8*)(qb + kw * 16);
    }

    f32x16 Ot[4] = {};
    float mi = -1e30f, li = 0.f;

    const int krow = lane >> 4, kslot = lane & 15;
    const int vrow = lane >> 3, vslot = lane & 7;

#define STAGE(BUF, KV0) do {                                                                  \
        const int kr0 = w * 8 + krow;                                                         \
        glds16(kg + (long long)((KV0) + kr0) * 128 + ((kslot ^ (kr0 & 7)) * 8),               \
               &Ksm[BUF][(w * 8) * 128]);                                                     \
        const int kr1 = kr0 + 4;                                                              \
        glds16(kg + (long long)((KV0) + kr1) * 128 + ((kslot ^ (kr1 & 7)) * 8),               \
               &Ksm[BUF][(w * 8 + 4) * 128]);                                                 \
        const int vd0 = w * 16 + vrow;                                                        \
        glds16(vg + (long long)vd0 * 2048 + (KV0) + ((vslot ^ (vrow & 7)) * 8),               \
               &Vsm[BUF][(w * 16) * 64]);                                                     \
        const int vd1 = vd0 + 8;                                                              \
        glds16(vg + (long long)vd1 * 2048 + (KV0) + ((vslot ^ (vrow & 7)) * 8),               \
               &Vsm[BUF][(w * 16 + 8) * 64]);                                                 \
    } while (0)

    STAGE(0, 0);
    __syncthreads();

    int buf = 0;
    for (int tt = 0; tt < 32; ++tt) {
        if (tt < 31) STAGE(buf ^ 1, tt * 64 + 64);

        f32x16 s0 = {}, s1 = {};
        __builtin_amdgcn_s_setprio(1);
#pragma unroll
        for (int kw = 0; kw < 8; ++kw) {
            const int sl = ((kw * 2 + half) ^ (q32 & 7)) * 8;
            bf16x8 k0 = *(const bf16x8*)(&Ksm[buf][q32 * 128 + sl]);
            bf16x8 k1 = *(const bf16x8*)(&Ksm[buf][(32 + q32) * 128 + sl]);
            s0 = MFMA32(k0, qf[kw], s0);
            s1 = MFMA32(k1, qf[kw], s1);
        }
        __builtin_amdgcn_s_setprio(0);

        const unsigned long long mw = mrow[tt];
        if (mw) {
#pragma unroll
            for (int g = 0; g < 4; ++g)
#pragma unroll
                for (int j = 0; j < 4; ++j) {
                    const int kl = j + 8 * g + 4 * half;
                    if ((mw >> kl) & 1) s0[g * 4 + j] = -1e30f;
                    if ((mw >> (32 + kl)) & 1) s1[g * 4 + j] = -1e30f;
                }
        }

        float m0 = fmaxf(s0[0], s1[0]), m1 = fmaxf(s0[1], s1[1]);
        float m2 = fmaxf(s0[2], s1[2]), m3 = fmaxf(s0[3], s1[3]);
#pragma unroll
        for (int i = 4; i < 16; i += 4) {
            m0 = fmaxf(m0, fmaxf(s0[i + 0], s1[i + 0]));
            m1 = fmaxf(m1, fmaxf(s0[i + 1], s1[i + 1]));
            m2 = fmaxf(m2, fmaxf(s0[i + 2], s1[i + 2]));
            m3 = fmaxf(m3, fmaxf(s0[i + 3], s1[i + 3]));
        }
        float mx = fmaxf(fmaxf(m0, m1), fmaxf(m2, m3));
        {
            auto r = __builtin_amdgcn_permlane32_swap(__builtin_bit_cast(unsigned, mx),
                                                      __builtin_bit_cast(unsigned, mx), false, false);
            mx = fmaxf(mx, fmaxf(__builtin_bit_cast(float, (unsigned)r[0]),
                                 __builtin_bit_cast(float, (unsigned)r[1])));
        }

        if (__any(mx > mi + 8.f)) {
            const float mnew = fmaxf(mi, mx);
            const float al = exp2f(mi - mnew);
            mi = mnew;
            li *= al;
#pragma unroll
            for (int dt = 0; dt < 4; ++dt)
#pragma unroll
                for (int i = 0; i < 16; ++i) Ot[dt][i] *= al;
        }

        float a0 = 0.f, a1 = 0.f, a2 = 0.f, a3 = 0.f;
#pragma unroll
        for (int i = 0; i < 16; i += 4) {
            float p;
            p = exp2f(s0[i + 0] - mi); s0[i + 0] = p; a0 += p;
            p = exp2f(s0[i + 1] - mi); s0[i + 1] = p; a1 += p;
            p = exp2f(s0[i + 2] - mi); s0[i + 2] = p; a2 += p;
            p = exp2f(s0[i + 3] - mi); s0[i + 3] = p; a3 += p;
            p = exp2f(s1[i + 0] - mi); s1[i + 0] = p; a0 += p;
            p = exp2f(s1[i + 1] - mi); s1[i + 1] = p; a1 += p;
            p = exp2f(s1[i + 2] - mi); s1[i + 2] = p; a2 += p;
            p = exp2f(s1[i + 3] - mi); s1[i + 3] = p; a3 += p;
        }
        float sum = (a0 + a1) + (a2 + a3);
        {
            auto r = __builtin_amdgcn_permlane32_swap(__builtin_bit_cast(unsigned, sum),
                                                      __builtin_bit_cast(unsigned, sum), false, false);
            sum += __builtin_bit_cast(float, (unsigned)(half ? r[0] : r[1]));
        }
        li += sum;

        bf16x8 pf[4];
#pragma unroll
        for (int s32 = 0; s32 < 2; ++s32)
#pragma unroll
            for (int wp = 0; wp < 2; ++wp) {
                const f32x16& st = s32 ? s1 : s0;
                unsigned xa = cvtpk_bf16(st[8 * wp + 0], st[8 * wp + 1]);
                unsigned xb = cvtpk_bf16(st[8 * wp + 2], st[8 * wp + 3]);
                unsigned ya = cvtpk_bf16(st[8 * wp + 4], st[8 * wp + 5]);
                unsigned yb = cvtpk_bf16(st[8 * wp + 6], st[8 * wp + 7]);
                auto rA = __builtin_amdgcn_permlane32_swap(xa, ya, false, false);
                auto rB = __builtin_amdgcn_permlane32_swap(xb, yb, false, false);
                u32x4v fw;
                fw[0] = (unsigned)rA[0]; fw[1] = (unsigned)rB[0];
                fw[2] = (unsigned)rA[1]; fw[3] = (unsigned)rB[1];
                pf[s32 * 2 + wp] = __builtin_bit_cast(bf16x8, fw);
            }

        __builtin_amdgcn_s_setprio(1);
#pragma unroll
        for (int kvw = 0; kvw < 4; ++kvw) {
            const int sl = ((kvw * 2 + half) ^ (q32 & 7)) * 8;
#pragma unroll
            for (int dt = 0; dt < 4; ++dt) {
                bf16x8 vf = *(const bf16x8*)(&Vsm[buf][(dt * 32 + q32) * 64 + sl]);
                Ot[dt] = MFMA32(vf, pf[kvw], Ot[dt]);
            }
        }
        __builtin_amdgcn_s_setprio(0);

        __syncthreads();
        buf ^= 1;
    }
#undef STAGE

    const float inv = 1.f / li;
    const long long token = (long long)b * 1024 + qt * 256 + w * 32 + q32;
    bf16* ao = AO + token * 4096 + h * 128 + half * 4;
#pragma unroll
    for (int dt = 0; dt < 4; ++dt)
#pragma unroll
        for (int g = 0; g < 4; ++g) {
            u16x4v pk;
#pragma unroll
            for (int j = 0; j < 4; ++j)
                pk[j] = __builtin_bit_cast(unsigned short, (bf16)(Ot[dt][g * 4 + j] * inv));
            *(u16x4v*)(ao + dt * 32 + g * 8) = pk;
        }
}

// ---------- host launch ----------
extern "C" void kernel_launch(void* const* d_in, const int* in_sizes, int n_in,
                              void* d_out, int out_size, void* d_ws, size_t ws_size,
                              hipStream_t stream) {
    const float* hidden = (const float*)d_in[0];
    const float* past_k = (const float*)d_in[1];
    const float* past_v = (const float*)d_in[2];
    const int*   amask  = (const int*)d_in[3];
    const float* Wq = (const float*)d_in[4];
    const float* bq = (const float*)d_in[5];
    const float* Wk = (const float*)d_in[6];
    const float* bk = (const float*)d_in[7];
    const float* Wv = (const float*)d_in[8];
    const float* bv = (const float*)d_in[9];
    const float* Wo = (const float*)d_in[10];
    const float* bo = (const float*)d_in[11];

    // workspace layout (128 MB total)
    char* ws = (char*)d_ws;
    bf16* Xb  = (bf16*)(ws);                     // 32 MB  hidden bf16 [4096][4096]
    bf16* Wqb = (bf16*)(ws + (1ll << 25));       // 32 MB: Wq bf16, later reused for Wo
    bf16* Kb  = (bf16*)(ws + (1ll << 26));       // 64MB:  K cache bf16 [4][8][2048][128]
    bf16* Vtb = (bf16*)(ws + (1ll << 26) + (1ll << 24)); // 80MB: V^T cache [4][8][128][2048]
    bf16* AOb = (bf16*)(ws + (3ll << 25));       // 96MB:  attention out bf16 [4096][4096]
    // scratch inside d_out (64MB, dead before final GEMM writes it)
    char* oc = (char*)d_out;
    bf16* Qb  = (bf16*)(oc);                     // 32 MB: scaled Q bf16 [4][32][1024][128]
    bf16* Wkb = (bf16*)(oc + (1ll << 25));       // 8 MB
    bf16* Wvb = (bf16*)(oc + (1ll << 25) + (1ll << 23)); // 8 MB
    unsigned long long* mpk = (unsigned long long*)(oc + (3ll << 24)); // 48MB: packed mask, 1KB

    const float qscale = 0.08838834764831845f * 1.44269504088896340f; // 1/sqrt(128) * log2(e)

    cvt_bf16_k<<<8192, 256, 0, stream>>>(hidden, Xb, 16777216ll);
    cvt_bf16_k<<<8192, 256, 0, stream>>>(Wq, Wqb, 16777216ll);
    cvt_bf16_k<<<2048, 256, 0, stream>>>(Wk, Wkb, 4194304ll);
    cvt_bf16_k<<<2048, 256, 0, stream>>>(Wv, Wvb, 4194304ll);
    cvt_pastk_k<<<2048, 256, 0, stream>>>(past_k, Kb);
    cvt_pastv_k<<<4096, 256, 0, stream>>>(past_v, Vtb);
    pack_mask_k<<<1, 128, 0, stream>>>(amask, mpk);

    gemm256<4><<<dim3(16, 16), 512, 0, stream>>>(Xb, Wqb, bq, (void*)Qb, 4096, 4096, 4096, qscale);
    gemm_bt<2><<<dim3(8, 32), 256, 0, stream>>>(Xb, Wkb, bk, (void*)Kb, 4096, 1024, 4096, 1.0f);
    gemm_bt<3><<<dim3(8, 32), 256, 0, stream>>>(Xb, Wvb, bv, (void*)Vtb, 4096, 1024, 4096, 1.0f);

    // Wo -> bf16 (reuse Wqb buffer; stream-ordered after Q projection consumed it)
    cvt_bf16_k<<<8192, 256, 0, stream>>>(Wo, Wqb, 16777216ll);

    attn_k<<<512, 512, 0, stream>>>(Qb, Kb, Vtb, mpk, AOb);

    gemm256<1><<<dim3(16, 16), 512, 0, stream>>>(AOb, Wqb, bo, d_out, 4096, 4096, 4096, 1.0f);
}

// Round 3
// 796.144 us; speedup vs baseline: 1.6063x; 1.1175x over previous
//
#include <hip/hip_runtime.h>
#include <cstdint>
#include <cstddef>

// ---------- types ----------
typedef __bf16 bf16;
typedef __bf16 bf16x8 __attribute__((ext_vector_type(8)));
typedef float  f32x4  __attribute__((ext_vector_type(4)));
typedef float  f32x16 __attribute__((ext_vector_type(16)));
typedef unsigned short u16x4v __attribute__((ext_vector_type(4)));
typedef unsigned int   u32x4v __attribute__((ext_vector_type(4)));

#define MFMA16(a, b, c) __builtin_amdgcn_mfma_f32_16x16x32_bf16((a), (b), (c), 0, 0, 0)
#define MFMA32(a, b, c) __builtin_amdgcn_mfma_f32_32x32x16_bf16((a), (b), (c), 0, 0, 0)

// async global->LDS, 16B per lane. LDS dst is wave-uniform base + lane*16 (HW adds lane part).
__device__ __forceinline__ void glds16(const bf16* g, bf16* l) {
    __builtin_amdgcn_global_load_lds(
        (__attribute__((address_space(1))) void*)(g),
        (__attribute__((address_space(3))) void*)(l), 16, 0, 0);
}

// pack two f32 -> one u32 of 2x bf16 (no builtin on gfx950; guide T12)
__device__ __forceinline__ unsigned cvtpk_bf16(float lo, float hi) {
    unsigned r;
    asm("v_cvt_pk_bf16_f32 %0, %1, %2" : "=v"(r) : "v"(lo), "v"(hi));
    return r;
}

// ---------- conversion kernels ----------
// generic f32 -> bf16 (used for Wo mid-pipeline)
__global__ __launch_bounds__(256) void cvt_bf16_k(const float* __restrict__ in,
                                                  bf16* __restrict__ out, long long n) {
    long long i = ((long long)blockIdx.x * 256 + threadIdx.x) * 8;
    if (i >= n) return;
    const float4* p = (const float4*)(in + i);
    float4 a = p[0], b = p[1];
    bf16x8 o;
    o[0] = (bf16)a.x; o[1] = (bf16)a.y; o[2] = (bf16)a.z; o[3] = (bf16)a.w;
    o[4] = (bf16)b.x; o[5] = (bf16)b.y; o[6] = (bf16)b.z; o[7] = (bf16)b.w;
    *(bf16x8*)(out + i) = o;
}

// fused: hidden -> Xb | Wq -> Wqb | Wk -> Wkvb[0:1024) | Wv -> Wkvb[1024:2048) | past_k -> Kb rows 0..1023
// segment boundaries are multiples of 8, so a thread never straddles.
__global__ __launch_bounds__(256) void fused_cvt_k(const float* __restrict__ hidden,
                                                   const float* __restrict__ Wq,
                                                   const float* __restrict__ Wk,
                                                   const float* __restrict__ Wv,
                                                   const float* __restrict__ past_k,
                                                   bf16* __restrict__ Xb,
                                                   bf16* __restrict__ Wqb,
                                                   bf16* __restrict__ Wkvb,
                                                   bf16* __restrict__ Kb) {
    long long e = ((long long)blockIdx.x * 256 + threadIdx.x) * 8;
    const float* src;
    bf16* dst;
    if (e < 16777216ll) {                       // hidden [4][1024][4096]
        src = hidden + e;           dst = Xb + e;
    } else if (e < 33554432ll) {                // Wq [4096][4096]
        long long i = e - 16777216ll;
        src = Wq + i;               dst = Wqb + i;
    } else if (e < 37748736ll) {                // Wk [1024][4096]
        long long i = e - 33554432ll;
        src = Wk + i;               dst = Wkvb + i;
    } else if (e < 41943040ll) {                // Wv [1024][4096]
        long long i = e - 37748736ll;
        src = Wv + i;               dst = Wkvb + 4194304ll + i;
    } else {                                    // past_k [4][8][1024][128] -> Kb [4][8][2048][128] rows 0..1023
        long long i = e - 41943040ll;
        src = past_k + i;
        dst = Kb + (i >> 17) * 262144ll + (i & 131071ll);
    }
    const float4* p = (const float4*)src;
    float4 a = p[0], b = p[1];
    bf16x8 o;
    o[0] = (bf16)a.x; o[1] = (bf16)a.y; o[2] = (bf16)a.z; o[3] = (bf16)a.w;
    o[4] = (bf16)b.x; o[5] = (bf16)b.y; o[6] = (bf16)b.z; o[7] = (bf16)b.w;
    *(bf16x8*)dst = o;
}

// past_v [4][8][1024][128] f32 -> Vt [4][8][128][2048] bf16 (transposed, first 1024 cols)
__global__ __launch_bounds__(256) void cvt_pastv_k(const float* __restrict__ in,
                                                   bf16* __restrict__ Vt) {
    const int tid = blockIdx.x * 256 + threadIdx.x;
    const int d   = tid & 127;
    const int kv4 = (tid >> 7) & 255;
    const int bh  = tid >> 15;
    u16x4v pk;
#pragma unroll
    for (int r = 0; r < 4; ++r) {
        float v = in[((long long)bh * 1024 + kv4 * 4 + r) * 128 + d];
        pk[r] = __builtin_bit_cast(unsigned short, (bf16)v);
    }
    *(u16x4v*)(Vt + ((long long)bh * 128 + d) * 2048 + kv4 * 4) = pk;
}

// ---------- fused K+V projection, 128x128 tile, N=2048 ----------
// n<1024: K rows -> K-cache [b][h][2048][128] at rows 1024+s
// n>=1024: V rows -> Vt [b][h][128][2048] at cols 1024+s (transposed, vectorized)
__global__ __launch_bounds__(256) void gemm_kv(const bf16* __restrict__ A,
                                               const bf16* __restrict__ B,
                                               const float* __restrict__ bk,
                                               const float* __restrict__ bv,
                                               bf16* __restrict__ Kc,
                                               bf16* __restrict__ Vt,
                                               int K) {
    __shared__ bf16 Asm[128 * 32];
    __shared__ bf16 Bsm[128 * 32];
    const int t = threadIdx.x;
    const int lane = t & 63, w = t >> 6;
    const int quad = lane >> 4, l16 = lane & 15;
    const int wr = (w >> 1) * 64, wc = (w & 1) * 64;
    const long long m0 = (long long)blockIdx.y * 128, n0 = (long long)blockIdx.x * 128;

    f32x4 acc[4][4] = {};

    const int i1 = t, i2 = t + 256;
    const bf16* gA1 = A + (m0 + (i1 >> 2)) * K + (i1 & 3) * 8;
    const bf16* gA2 = A + (m0 + (i2 >> 2)) * K + (i2 & 3) * 8;
    const bf16* gB1 = B + (n0 + (i1 >> 2)) * K + (i1 & 3) * 8;
    const bf16* gB2 = B + (n0 + (i2 >> 2)) * K + (i2 & 3) * 8;
    bf16* lA1 = Asm + i1 * 8;
    bf16* lA2 = Asm + i2 * 8;
    bf16* lB1 = Bsm + i1 * 8;
    bf16* lB2 = Bsm + i2 * 8;

    for (int k0 = 0; k0 < K; k0 += 32) {
        glds16(gA1 + k0, lA1);
        glds16(gA2 + k0, lA2);
        glds16(gB1 + k0, lB1);
        glds16(gB2 + k0, lB2);
        __syncthreads();
        bf16x8 af[4], bfr[4];
#pragma unroll
        for (int i = 0; i < 4; ++i)
            af[i] = *(const bf16x8*)(Asm + (wr + i * 16 + l16) * 32 + quad * 8);
#pragma unroll
        for (int j = 0; j < 4; ++j)
            bfr[j] = *(const bf16x8*)(Bsm + (wc + j * 16 + l16) * 32 + quad * 8);
#pragma unroll
        for (int i = 0; i < 4; ++i)
#pragma unroll
            for (int j = 0; j < 4; ++j)
                acc[i][j] = MFMA16(af[i], bfr[j], acc[i][j]);
        __syncthreads();
    }

    const bool isK = (n0 < 1024);
    const long long c0 = isK ? n0 : (n0 - 1024);
    const float* bias = isK ? (bk + c0) : (bv + c0);

    float bs[4];
#pragma unroll
    for (int j = 0; j < 4; ++j) bs[j] = bias[wc + j * 16 + l16];

#pragma unroll
    for (int i = 0; i < 4; ++i) {
        const long long mbase = m0 + wr + i * 16 + quad * 4;
#pragma unroll
        for (int j = 0; j < 4; ++j) {
            const long long col = c0 + wc + j * 16 + l16;
            const int h = (int)(col >> 7), d = (int)(col & 127);
            if (isK) {
#pragma unroll
                for (int r = 0; r < 4; ++r) {
                    const long long m = mbase + r;
                    const long long bb = m >> 10, s = m & 1023;
                    Kc[((bb * 8 + h) * 2048 + 1024 + s) * 128 + d] = (bf16)(acc[i][j][r] + bs[j]);
                }
            } else {
                const long long bb = mbase >> 10, s = mbase & 1023;
                u16x4v pk;
#pragma unroll
                for (int r = 0; r < 4; ++r)
                    pk[r] = __builtin_bit_cast(unsigned short, (bf16)(acc[i][j][r] + bs[j]));
                *(u16x4v*)(Vt + ((bb * 8 + h) * 128 + d) * 2048 + 1024 + s) = pk;
            }
        }
    }
}

// ---------- 256x256-tile deep-pipelined GEMM (big projections) ----------
// 8 waves (2M x 4N), BK=32, 4-deep LDS ring, counted vmcnt(8), T2 swizzle, T5 setprio.
// MODE 1: f32 row-major out, acc+bias           (output projection)
// MODE 4: bf16 out scattered into Qs [b][h][1024][128], (acc+bias)*scale  (Q projection)
template <int MODE>
__global__ __launch_bounds__(512, 2) void gemm256(const bf16* __restrict__ A,
                                                  const bf16* __restrict__ B,
                                                  const float* __restrict__ bias,
                                                  void* __restrict__ Cv,
                                                  int M, int N, int K, float scale) {
    __shared__ bf16 S[4][16384];   // 4 buffers x (A 8192 + B 8192) elems = 128 KiB
    const int t = threadIdx.x, lane = t & 63, w = t >> 6;
    const int quad = lane >> 4, l16 = lane & 15;
    const int wm = w >> 2, wn = w & 3;

    // XCD-chunked bijective swizzle (nwg % 8 == 0 for all our launches)
    const int nwg = gridDim.x * gridDim.y;
    const int bid = blockIdx.y * gridDim.x + blockIdx.x;
    const int lid = (bid & 7) * (nwg >> 3) + (bid >> 3);
    const long long m0 = (long long)(lid / gridDim.x) * 256;
    const long long n0 = (long long)(lid % gridDim.x) * 256;

    // staging geometry: chunk c = 16 rows (8 lines); lane l writes phys slot l&7 of line 8c+(l>>3)
    const int sA   = (lane & 7) ^ (lane >> 3);
    const int rsub = 2 * (lane >> 3) + (sA >> 2);
    const int colk = (sA & 3) * 8;
    const int c0 = w * 2, c1 = w * 2 + 1;
    const long long gA0 = (m0 + c0 * 16 + rsub) * (long long)K + colk;
    const long long gA1 = (m0 + c1 * 16 + rsub) * (long long)K + colk;
    const long long gB0 = (n0 + c0 * 16 + rsub) * (long long)K + colk;
    const long long gB1 = (n0 + c1 * 16 + rsub) * (long long)K + colk;

    // read geometry
    const int lA7   = l16 >> 1;
    const int slotE = ((((l16 & 1) * 4 + quad) ^ lA7) * 16) >> 1;
    const int baseAe = (wm * 64 + lA7) * 64 + slotE;
    const int baseBe = (wn * 32 + lA7) * 64 + slotE;

    f32x4 acc[8][4] = {};

    auto stg = [&](int bufi, int tile) {
        const long long kk = (long long)tile * 32;
        bf16* sb = &S[bufi][0];
        glds16(A + gA0 + kk, sb + c0 * 512);
        glds16(A + gA1 + kk, sb + c1 * 512);
        glds16(B + gB0 + kk, sb + 8192 + c0 * 512);
        glds16(B + gB1 + kk, sb + 8192 + c1 * 512);
    };
    auto compute = [&](int tt) {
        const bf16* pA = &S[tt & 3][baseAe];
        const bf16* pB = &S[tt & 3][8192 + baseBe];
        bf16x8 af[8], bfr[4];
#pragma unroll
        for (int m = 0; m < 8; ++m) af[m] = *(const bf16x8*)(pA + m * 512);
#pragma unroll
        for (int n = 0; n < 4; ++n) bfr[n] = *(const bf16x8*)(pB + n * 512);
        __builtin_amdgcn_s_setprio(1);
#pragma unroll
        for (int m = 0; m < 8; ++m)
#pragma unroll
            for (int n = 0; n < 4; ++n)
                acc[m][n] = MFMA16(af[m], bfr[n], acc[m][n]);
        __builtin_amdgcn_s_setprio(0);
    };

    const int nt = K >> 5;   // 128 for K=4096

    stg(0, 0); stg(1, 1); stg(2, 2);
    asm volatile("s_waitcnt vmcnt(8)" ::: "memory");
    asm volatile("s_barrier" ::: "memory");

    for (int tt = 0; tt + 3 < nt; ++tt) {
        stg((tt + 3) & 3, tt + 3);
        compute(tt);
        asm volatile("s_waitcnt vmcnt(8)" ::: "memory");
        asm volatile("s_barrier" ::: "memory");
    }
    compute(nt - 3);
    asm volatile("s_waitcnt vmcnt(4)" ::: "memory");
    asm volatile("s_barrier" ::: "memory");
    compute(nt - 2);
    asm volatile("s_waitcnt vmcnt(0)" ::: "memory");
    asm volatile("s_barrier" ::: "memory");
    compute(nt - 1);

    // ---- epilogue ----
    float bs[4];
#pragma unroll
    for (int n = 0; n < 4; ++n) bs[n] = bias[n0 + wn * 64 + n * 16 + l16];

#pragma unroll
    for (int m = 0; m < 8; ++m) {
        const long long mbase = m0 + wm * 128 + m * 16 + quad * 4;
#pragma unroll
        for (int n = 0; n < 4; ++n) {
            const long long nn = n0 + wn * 64 + n * 16 + l16;
            if (MODE == 1) {
                float* Cf = (float*)Cv;
#pragma unroll
                for (int r = 0; r < 4; ++r)
                    Cf[(mbase + r) * N + nn] = acc[m][n][r] + bs[n];
            } else {  // MODE 4: Qs [b][h][1024][128] bf16, scaled
                bf16* Cq = (bf16*)Cv;
                const int h = (int)(nn >> 7), d = (int)(nn & 127);
#pragma unroll
                for (int r = 0; r < 4; ++r) {
                    const long long mr = mbase + r;
                    const long long bb = mr >> 10, s = mr & 1023;
                    Cq[((bb * 32 + h) * 1024 + s) * 128 + d] = (bf16)((acc[m][n][r] + bs[n]) * scale);
                }
            }
        }
    }
}

// ---------- flash attention (8-wave, 32x32 swapped-MFMA, in-register softmax) ----------
// mask packed in-kernel: 4 ballots/wave -> Msm[32] of u64 (bit=1 means MASKED)
__global__ __launch_bounds__(512, 2) void attn_k(const bf16* __restrict__ Qs,
                                                 const bf16* __restrict__ Kc,
                                                 const bf16* __restrict__ Vt,
                                                 const int* __restrict__ amask,
                                                 bf16* __restrict__ AO) {
    const int phys = blockIdx.x;
    const int lid = (phys & 7) * 64 + (phys >> 3);
    const int qt = lid & 3, h = (lid >> 2) & 31, b = lid >> 7;
    const int hk = h >> 2;
    const int t = threadIdx.x, lane = t & 63, w = t >> 6;
    const int q32 = lane & 31, half = lane >> 5;

    __shared__ bf16 Ksm[2][64 * 128];   // [kv][d], XOR-swizzled 16B slots: slot ^= row&7
    __shared__ bf16 Vsm[2][128 * 64];   // [d][kv], XOR-swizzled 16B slots: slot ^= row&7
    __shared__ unsigned long long Msm[32];

    const bf16* kg = Kc + (long long)(b * 8 + hk) * 2048 * 128;
    const bf16* vg = Vt + (long long)(b * 8 + hk) * 128 * 2048;

    // pack attention mask: word tt covers kv = tt*64 + bit
    {
        const int* am = amask + b * 2048;
#pragma unroll
        for (int j = 0; j < 4; ++j) {
            unsigned long long bm = __ballot(am[w * 256 + j * 64 + lane] != 0);
            if (lane == 0) Msm[w * 4 + j] = bm;
        }
    }

    bf16x8 qf[8];
    {
        const bf16* qb = Qs + ((long long)(b * 32 + h) * 1024 + qt * 256 + w * 32 + q32) * 128 + half * 8;
#pragma unroll
        for (int kw = 0; kw < 8; ++kw) qf[kw] = *(const bf16x8*)(qb + kw * 16);
    }

    f32x16 Ot[4] = {};
    float mi = -1e30f, li = 0.f;

    const int krow = lane >> 4, kslot = lane & 15;
    const int vrow = lane >> 3, vslot = lane & 7;

#define STAGE(BUF, KV0) do {                                                                  \
        const int kr0 = w * 8 + krow;                                                         \
        glds16(kg + (long long)((KV0) + kr0) * 128 + ((kslot ^ (kr0 & 7)) * 8),               \
               &Ksm[BUF][(w * 8) * 128]);                                                     \
        const int kr1 = kr0 + 4;                                                              \
        glds16(kg + (long long)((KV0) + kr1) * 128 + ((kslot ^ (kr1 & 7)) * 8),               \
               &Ksm[BUF][(w * 8 + 4) * 128]);                                                 \
        const int vd0 = w * 16 + vrow;                                                        \
        glds16(vg + (long long)vd0 * 2048 + (KV0) + ((vslot ^ (vrow & 7)) * 8),               \
               &Vsm[BUF][(w * 16) * 64]);                                                     \
        const int vd1 = vd0 + 8;                                                              \
        glds16(vg + (long long)vd1 * 2048 + (KV0) + ((vslot ^ (vrow & 7)) * 8),               \
               &Vsm[BUF][(w * 16 + 8) * 64]);                                                 \
    } while (0)

    STAGE(0, 0);
    __syncthreads();

    int buf = 0;
    for (int tt = 0; tt < 32; ++tt) {
        if (tt < 31) STAGE(buf ^ 1, tt * 64 + 64);

        f32x16 s0 = {}, s1 = {};
        __builtin_amdgcn_s_setprio(1);
#pragma unroll
        for (int kw = 0; kw < 8; ++kw) {
            const int sl = ((kw * 2 + half) ^ (q32 & 7)) * 8;
            bf16x8 k0 = *(const bf16x8*)(&Ksm[buf][q32 * 128 + sl]);
            bf16x8 k1 = *(const bf16x8*)(&Ksm[buf][(32 + q32) * 128 + sl]);
            s0 = MFMA32(k0, qf[kw], s0);
            s1 = MFMA32(k1, qf[kw], s1);
        }
        __builtin_amdgcn_s_setprio(0);

        const unsigned long long mw = Msm[tt];
        if (mw) {
#pragma unroll
            for (int g = 0; g < 4; ++g)
#pragma unroll
                for (int j = 0; j < 4; ++j) {
                    const int kl = j + 8 * g + 4 * half;
                    if ((mw >> kl) & 1) s0[g * 4 + j] = -1e30f;
                    if ((mw >> (32 + kl)) & 1) s1[g * 4 + j] = -1e30f;
                }
        }

        float m0 = fmaxf(s0[0], s1[0]), m1 = fmaxf(s0[1], s1[1]);
        float m2 = fmaxf(s0[2], s1[2]), m3 = fmaxf(s0[3], s1[3]);
#pragma unroll
        for (int i = 4; i < 16; i += 4) {
            m0 = fmaxf(m0, fmaxf(s0[i + 0], s1[i + 0]));
            m1 = fmaxf(m1, fmaxf(s0[i + 1], s1[i + 1]));
            m2 = fmaxf(m2, fmaxf(s0[i + 2], s1[i + 2]));
            m3 = fmaxf(m3, fmaxf(s0[i + 3], s1[i + 3]));
        }
        float mx = fmaxf(fmaxf(m0, m1), fmaxf(m2, m3));
        {
            auto r = __builtin_amdgcn_permlane32_swap(__builtin_bit_cast(unsigned, mx),
                                                      __builtin_bit_cast(unsigned, mx), false, false);
            mx = fmaxf(mx, fmaxf(__builtin_bit_cast(float, (unsigned)r[0]),
                                 __builtin_bit_cast(float, (unsigned)r[1])));
        }

        if (__any(mx > mi + 8.f)) {
            const float mnew = fmaxf(mi, mx);
            const float al = exp2f(mi - mnew);
            mi = mnew;
            li *= al;
#pragma unroll
            for (int dt = 0; dt < 4; ++dt)
#pragma unroll
                for (int i = 0; i < 16; ++i) Ot[dt][i] *= al;
        }

        float a0 = 0.f, a1 = 0.f, a2 = 0.f, a3 = 0.f;
#pragma unroll
        for (int i = 0; i < 16; i += 4) {
            float p;
            p = exp2f(s0[i + 0] - mi); s0[i + 0] = p; a0 += p;
            p = exp2f(s0[i + 1] - mi); s0[i + 1] = p; a1 += p;
            p = exp2f(s0[i + 2] - mi); s0[i + 2] = p; a2 += p;
            p = exp2f(s0[i + 3] - mi); s0[i + 3] = p; a3 += p;
            p = exp2f(s1[i + 0] - mi); s1[i + 0] = p; a0 += p;
            p = exp2f(s1[i + 1] - mi); s1[i + 1] = p; a1 += p;
            p = exp2f(s1[i + 2] - mi); s1[i + 2] = p; a2 += p;
            p = exp2f(s1[i + 3] - mi); s1[i + 3] = p; a3 += p;
        }
        float sum = (a0 + a1) + (a2 + a3);
        {
            auto r = __builtin_amdgcn_permlane32_swap(__builtin_bit_cast(unsigned, sum),
                                                      __builtin_bit_cast(unsigned, sum), false, false);
            sum += __builtin_bit_cast(float, (unsigned)(half ? r[0] : r[1]));
        }
        li += sum;

        bf16x8 pf[4];
#pragma unroll
        for (int s32 = 0; s32 < 2; ++s32)
#pragma unroll
            for (int wp = 0; wp < 2; ++wp) {
                const f32x16& st = s32 ? s1 : s0;
                unsigned xa = cvtpk_bf16(st[8 * wp + 0], st[8 * wp + 1]);
                unsigned xb = cvtpk_bf16(st[8 * wp + 2], st[8 * wp + 3]);
                unsigned ya = cvtpk_bf16(st[8 * wp + 4], st[8 * wp + 5]);
                unsigned yb = cvtpk_bf16(st[8 * wp + 6], st[8 * wp + 7]);
                auto rA = __builtin_amdgcn_permlane32_swap(xa, ya, false, false);
                auto rB = __builtin_amdgcn_permlane32_swap(xb, yb, false, false);
                u32x4v fw;
                fw[0] = (unsigned)rA[0]; fw[1] = (unsigned)rB[0];
                fw[2] = (unsigned)rA[1]; fw[3] = (unsigned)rB[1];
                pf[s32 * 2 + wp] = __builtin_bit_cast(bf16x8, fw);
            }

        __builtin_amdgcn_s_setprio(1);
#pragma unroll
        for (int kvw = 0; kvw < 4; ++kvw) {
            const int sl = ((kvw * 2 + half) ^ (q32 & 7)) * 8;
#pragma unroll
            for (int dt = 0; dt < 4; ++dt) {
                bf16x8 vf = *(const bf16x8*)(&Vsm[buf][(dt * 32 + q32) * 64 + sl]);
                Ot[dt] = MFMA32(vf, pf[kvw], Ot[dt]);
            }
        }
        __builtin_amdgcn_s_setprio(0);

        __syncthreads();
        buf ^= 1;
    }
#undef STAGE

    const float inv = 1.f / li;
    const long long token = (long long)b * 1024 + qt * 256 + w * 32 + q32;
    bf16* ao = AO + token * 4096 + h * 128 + half * 4;
#pragma unroll
    for (int dt = 0; dt < 4; ++dt)
#pragma unroll
        for (int g = 0; g < 4; ++g) {
            u16x4v pk;
#pragma unroll
            for (int j = 0; j < 4; ++j)
                pk[j] = __builtin_bit_cast(unsigned short, (bf16)(Ot[dt][g * 4 + j] * inv));
            *(u16x4v*)(ao + dt * 32 + g * 8) = pk;
        }
}

// ---------- host launch ----------
extern "C" void kernel_launch(void* const* d_in, const int* in_sizes, int n_in,
                              void* d_out, int out_size, void* d_ws, size_t ws_size,
                              hipStream_t stream) {
    const float* hidden = (const float*)d_in[0];
    const float* past_k = (const float*)d_in[1];
    const float* past_v = (const float*)d_in[2];
    const int*   amask  = (const int*)d_in[3];
    const float* Wq = (const float*)d_in[4];
    const float* bq = (const float*)d_in[5];
    const float* Wk = (const float*)d_in[6];
    const float* bk = (const float*)d_in[7];
    const float* Wv = (const float*)d_in[8];
    const float* bv = (const float*)d_in[9];
    const float* Wo = (const float*)d_in[10];
    const float* bo = (const float*)d_in[11];

    // workspace layout (128 MB total)
    char* ws = (char*)d_ws;
    bf16* Xb   = (bf16*)(ws);                             // 32MB  hidden bf16 [4096][4096]
    bf16* Wqb  = (bf16*)(ws + (1ll << 25));               // 32MB  Wq bf16, later reused for Wo
    bf16* Wkvb = (bf16*)(ws + (1ll << 26));               // 16MB  [Wk;Wv] bf16 [2048][4096]
    bf16* AOb  = (bf16*)(ws + (1ll << 26) + (1ll << 24)); // 32MB @80MB: attention out bf16
    // scratch inside d_out (64MB, dead before final GEMM writes it)
    char* oc = (char*)d_out;
    bf16* Qb  = (bf16*)(oc);                              // 32MB: scaled Q bf16 [4][32][1024][128]
    bf16* Kb  = (bf16*)(oc + (1ll << 25));                // 16MB: K cache [4][8][2048][128]
    bf16* Vtb = (bf16*)(oc + (1ll << 25) + (1ll << 24));  // 16MB: V^T cache [4][8][128][2048]

    const float qscale = 0.08838834764831845f * 1.44269504088896340f; // 1/sqrt(128) * log2(e)

    // fused conversions: hidden, Wq, Wk, Wv, past_k  (46137344 elems / 2048 per block)
    fused_cvt_k<<<22528, 256, 0, stream>>>(hidden, Wq, Wk, Wv, past_k, Xb, Wqb, Wkvb, Kb);
    cvt_pastv_k<<<4096, 256, 0, stream>>>(past_v, Vtb);

    gemm256<4><<<dim3(16, 16), 512, 0, stream>>>(Xb, Wqb, bq, (void*)Qb, 4096, 4096, 4096, qscale);
    gemm_kv<<<dim3(16, 32), 256, 0, stream>>>(Xb, Wkvb, bk, bv, Kb, Vtb, 4096);

    // Wo -> bf16 (reuse Wqb buffer; stream-ordered after Q projection consumed it)
    cvt_bf16_k<<<8192, 256, 0, stream>>>(Wo, Wqb, 16777216ll);

    attn_k<<<512, 512, 0, stream>>>(Qb, Kb, Vtb, amask, AOb);

    gemm256<1><<<dim3(16, 16), 512, 0, stream>>>(AOb, Wqb, bo, d_out, 4096, 4096, 4096, 1.0f);
}